// Round 11
// baseline (1492.635 us; speedup 1.0000x reference)
//
#include <hip/hip_runtime.h>
#include <hip/hip_bf16.h>
#include <string.h>

// Problem constants
#define B_ 64
#define T_ 256
#define F_ 64
#define U_ 512
#define G4_ 2048     // 4*U
#define KTOT 576     // F + U
#define KSTEPS 18    // KTOT/32

typedef __attribute__((ext_vector_type(8))) short short8;
typedef __attribute__((ext_vector_type(4))) float v4f;
typedef __attribute__((ext_vector_type(4))) int i4;
typedef unsigned short u16;

__device__ __forceinline__ float bf2f(u16 b) {
    unsigned int x = ((unsigned int)b) << 16;
    float f; memcpy(&f, &x, 4); return f;
}
__device__ __forceinline__ u16 f2bf(float f) {
    __hip_bfloat16 h = __float2bfloat16(f);
    u16 b; memcpy(&b, &h, 2); return b;
}
__device__ __forceinline__ float sigmoidf_(float x) { return 1.f / (1.f + __expf(-x)); }
__device__ __forceinline__ float tanhf_(float x) {   // clamped exp form (R8/R9-proven)
    float xc = fminf(15.f, fmaxf(-15.f, x));
    float e = __expf(2.f * xc);
    return (e - 1.f) / (e + 1.f);
}

// Dtype-flexible element load: fg=1 -> fp32, fg=0 -> bf16.
__device__ __forceinline__ float ldany(const void* p, size_t i, int fg) {
    return fg ? ((const float*)p)[i] : bf2f(((const u16*)p)[i]);
}

// Workspace layout (bytes; offsets 64-aligned) -- unchanged.
#define WS_FLAG   0             // int dtype-flag @0
#define WS_XB     64            // bf16 [T][B][F]          2,097,152
#define WS_WP     2097216       // bf16 packed weights     2,359,296
#define WS_H2     4456512       // bf16 [2][B][U]            131,072
#define WS_DOT    4718656       // fp32 [B][T]                65,536
#define WS_BIASF  4784192       // fp32 [4U]                   8,192
#define WS_ATTWF  4792384       // fp32 [T][T]               262,144
#define WS_ATTBF  5054528       // fp32 [T]                    1,024
#define WS_OUTWF  5055552       // fp32 [U]                    2,048
#define WS_OUTBF  5057600       // fp32 [1]                       64
#define WS_NEED   5057920

// ---------------------------------------------------------------------------
// Kernel 0: dtype detection (flag: 1 = fp32 inputs, 0 = bf16).
// ---------------------------------------------------------------------------
__global__ __launch_bounds__(256) void detect(const unsigned int* __restrict__ w,
                                              int* __restrict__ flag) {
    __shared__ int votes;
    if (threadIdx.x == 0) votes = 0;
    __syncthreads();
    unsigned int v = w[threadIdx.x];
    int e = (v >> 7) & 0xFF;
    if (e >= 100 && e <= 135) atomicAdd(&votes, 1);
    __syncthreads();
    if (threadIdx.x == 0) *flag = (votes < 200) ? 1 : 0;
}

// ---------------------------------------------------------------------------
// Kernel 1: canonicalize inputs.  x -> xb bf16 [T][B][F]; small arrays ->
// fp32; dot -> 0; h2 ping-pong -> 0 (tag 0 == stale for every expected tag;
// zeros are also the correct h_{-1} at t=0 where the check is skipped).
// ---------------------------------------------------------------------------
__global__ __launch_bounds__(256) void convert(const void* __restrict__ x,
                                               const void* __restrict__ bias,
                                               const void* __restrict__ attW,
                                               const void* __restrict__ attb,
                                               const void* __restrict__ outW,
                                               const void* __restrict__ outb,
                                               const int* __restrict__ flag,
                                               u16* __restrict__ xb,
                                               float* __restrict__ biasf,
                                               float* __restrict__ attWf,
                                               float* __restrict__ attbf,
                                               float* __restrict__ outWf,
                                               float* __restrict__ outbf,
                                               float* __restrict__ dot,
                                               unsigned int* __restrict__ h2z) {
    int fg = *flag;
    size_t i = (size_t)blockIdx.x * 256 + threadIdx.x;
    if (i < 1048576) {
        float v = ldany(x, i, fg);
        int b = (int)(i >> 14), t = (int)((i >> 6) & 255), f = (int)(i & 63);
        xb[((size_t)t * B_ + b) * F_ + f] = f2bf(v);
        return;
    }
    i -= 1048576;
    if (i < 2048)  { biasf[i] = ldany(bias, i, fg); return; }
    i -= 2048;
    if (i < 65536) { attWf[i] = ldany(attW, i, fg); return; }
    i -= 65536;
    if (i < 256)   { attbf[i] = ldany(attb, i, fg); return; }
    i -= 256;
    if (i < 512)   { outWf[i] = ldany(outW, i, fg); return; }
    i -= 512;
    if (i < 1)     { outbf[i] = ldany(outb, i, fg); return; }
    i -= 1;
    if (i < 16384) { dot[i] = 0.f; return; }
    i -= 16384;
    if (i < 32768) { h2z[i] = 0u; return; }   // both h ping-pong buffers
}

// ---------------------------------------------------------------------------
// Kernel 2: pack [kernel; rec_kernel] into MFMA-B fragments, cols c'=4u+gate.
// Lane l of fragment (nt, ks) supplies B[k=ks*32+(l>>4)*8+j][col=nt*16+(l&15)].
// ---------------------------------------------------------------------------
__global__ __launch_bounds__(256) void pack_w(const void* __restrict__ kin,
                                              const void* __restrict__ krec,
                                              const int* __restrict__ flag,
                                              u16* __restrict__ Wp) {
    int fg = *flag;
    int gid = blockIdx.x * 256 + threadIdx.x;   // grid = 576*256 == 128*18*64
    int lane = gid & 63;
    int frag = gid >> 6;
    int nt = frag / KSTEPS;
    int ks = frag - nt * KSTEPS;
    int kbase = ks * 32 + (lane >> 4) * 8;
    int cp = nt * 16 + (lane & 15);
    int u = cp >> 2, gate = cp & 3;
    int C = gate * U_ + u;
    short8 v;
    for (int j = 0; j < 8; j++) {
        int k = kbase + j;
        float w = (k < F_) ? ldany(kin, (size_t)k * G4_ + C, fg)
                           : ldany(krec, (size_t)(k - F_) * G4_ + C, fg);
        v[j] = (short)f2bf(w);
    }
    *reinterpret_cast<short8*>(Wp + (size_t)gid * 8) = v;
}

// ---------------------------------------------------------------------------
// Kernel 3: PERSISTENT LSTM -- R10 partition + single-barrier shuffle epilogue.
// Grid 64 x 512 (8 waves).  Block = (rg = bid&3: 16 rows) x (gu = bid>>2:
// 32 units); wave w owns n-tile nt = gu*8+w (units 4nt..4nt+3), weights in
// W[18] (loaded once).  Per step: poll own 2 rows (2 coherent 16B loads/lane,
// R7-proven sc1 + in-band LSB tag mechanism) -> stage ping-pong LDS ->
// ONE barrier -> MFMA -> shuffle-gather gates within the wave (R8-verified
// mapping) -> c/h in registers (4 rows/lane, quad-redundant) -> IMMEDIATE
// per-wave sc1 h store (no block barrier on the store path).
//   Stage ping-pong safety: wave X rewrites stage[par] at t+2 only after
//   barrier(t+1), which requires every wave to have staged t+1, which (in
//   program order) is after their MFMA reads of stage[par] at t.  h-buffer
//   safety: X stores h(t+2) into buf[t&1] only after its poll of h(t+1)
//   passed, which requires every same-rg block to have stored h(t+1), which
//   is after their reads of h(t) from buf[t&1]; other-rg blocks touch
//   disjoint rows.  dot partials are wave-private (dp[w]), flushed per-wave
//   every 32 steps -- no barrier.
// ---------------------------------------------------------------------------
__global__ __launch_bounds__(512, 1) void lstm_persist(const u16* __restrict__ xb,
                                                       const float* __restrict__ biasf,
                                                       const float* __restrict__ outWf,
                                                       const u16* __restrict__ Wp,
                                                       u16* __restrict__ h2,
                                                       float* __restrict__ dot) {
    __shared__ __align__(16) u16 stage[2][16 * 520];  // ping-pong, 2 x 16.3 KB
    __shared__ float dp[8][32][16];                   // per-wave dot partials, 16 KB

    int tid = threadIdx.x;
    int bid = blockIdx.x;
    int rg = bid & 3;                     // row-group: rows [16rg, 16rg+16)
    int gu = bid >> 2;                    // unit-group: units [32gu, 32gu+32)
    int w = tid >> 6, l = tid & 63;
    int nt = gu * 8 + w;                  // this wave's global n-tile

    // Weights: 18 fragments per wave, loaded once.
    short8 W[KSTEPS];
    #pragma unroll
    for (int ks = 0; ks < KSTEPS; ks++)
        W[ks] = *reinterpret_cast<const short8*>(Wp + ((size_t)(nt * KSTEPS + ks) * 64 + l) * 8);

    // MFMA roles.
    int arow = rg * 16 + (l & 15);        // A row (global batch index)
    int koff = (l >> 4) * 8;              // k-chunk within a 32-wide ks
    // Poll/stage roles: wave w handles local rows 2w, 2w+1.
    int plr = 2 * w + (l >> 5);           // local row polled by this lane
    int pcol = (l & 31) * 16;             // u16 column of this lane's 32B chunk
    // Epilogue roles: lane computes unit ul = (l&15)>>2 for rows rb..rb+3.
    int ul = (l & 15) >> 2;
    int unit = 4 * nt + ul;               // global unit
    int rb = (l >> 4) * 4;                // local row base
    float bia = biasf[0 * U_ + unit], bif = biasf[1 * U_ + unit];
    float big = biasf[2 * U_ + unit], bio = biasf[3 * U_ + unit];
    float wout = outWf[unit];
    float creg[4] = {0.f, 0.f, 0.f, 0.f};
    int qb = l & ~3;                      // quad base for gate gather

    for (int t = 0; t < T_; t++) {
        u16* hcur = h2 + (size_t)(t & 1) * (B_ * U_);
        const u16* hprev = h2 + (size_t)((t + 1) & 1) * (B_ * U_);
        unsigned int wtag = ((unsigned)(t >> 1) & 1u) ^ 1u;
        unsigned int rpat = ((((unsigned)(t - 1) >> 1) & 1u) ^ 1u) * 0x00010001u;
        u16* stg = stage[t & 1];

        // x fragments + x-part MFMAs issue first (overlap staging/barrier).
        const u16* xrow = xb + ((size_t)t * B_ + arow) * F_;
        short8 a0 = *reinterpret_cast<const short8*>(xrow + koff);
        short8 a1 = *reinterpret_cast<const short8*>(xrow + 32 + koff);
        v4f acc0 = {0.f, 0.f, 0.f, 0.f}, acc1 = {0.f, 0.f, 0.f, 0.f};
        acc0 = __builtin_amdgcn_mfma_f32_16x16x32_bf16(a0, W[0], acc0, 0, 0, 0);
        acc1 = __builtin_amdgcn_mfma_f32_16x16x32_bf16(a1, W[1], acc1, 0, 0, 0);

        // Poll this wave's 2 rows of h_{t-1} (coherent, tag-gated).
        i4 q0, q1;
        {
            const void* bp = (const void*)(hprev + (size_t)(rg * 16 + plr) * U_ + pcol);
            int spins = 0;
            for (;;) {
                asm volatile(
                    "global_load_dwordx4 %0, %2, off sc0 sc1\n\t"
                    "global_load_dwordx4 %1, %2, off offset:16 sc0 sc1\n\t"
                    "s_waitcnt vmcnt(0)"
                    : "=v"(q0), "=v"(q1) : "v"(bp) : "memory");
                if (t == 0) break;        // zeros are the correct h_{-1}
                unsigned bad = 0;
                bad |= (((unsigned)q0[0]) ^ rpat) & 0x00010001u;
                bad |= (((unsigned)q0[1]) ^ rpat) & 0x00010001u;
                bad |= (((unsigned)q0[2]) ^ rpat) & 0x00010001u;
                bad |= (((unsigned)q0[3]) ^ rpat) & 0x00010001u;
                bad |= (((unsigned)q1[0]) ^ rpat) & 0x00010001u;
                bad |= (((unsigned)q1[1]) ^ rpat) & 0x00010001u;
                bad |= (((unsigned)q1[2]) ^ rpat) & 0x00010001u;
                bad |= (((unsigned)q1[3]) ^ rpat) & 0x00010001u;
                if (__ballot(bad == 0) == ~0ull) break;
                if (++spins > (1 << 14)) break;   // bailout: never hang
                __builtin_amdgcn_s_sleep(2);      // short backoff
            }
        }
        *reinterpret_cast<i4*>(&stg[plr * 520 + pcol])     = q0;
        *reinterpret_cast<i4*>(&stg[plr * 520 + pcol + 8]) = q1;
        __syncthreads();   // the single per-step barrier: stage ready

        // h-part MFMAs from staged LDS (two independent chains).
        #pragma unroll
        for (int ks = 2; ks < KSTEPS; ks += 2) {
            short8 ah0 = *reinterpret_cast<const short8*>(
                &stg[(l & 15) * 520 + (ks - 2) * 32 + koff]);
            short8 ah1 = *reinterpret_cast<const short8*>(
                &stg[(l & 15) * 520 + (ks - 1) * 32 + koff]);
            acc0 = __builtin_amdgcn_mfma_f32_16x16x32_bf16(ah0, W[ks],     acc0, 0, 0, 0);
            acc1 = __builtin_amdgcn_mfma_f32_16x16x32_bf16(ah1, W[ks + 1], acc1, 0, 0, 0);
        }
        v4f acc = acc0 + acc1;

        // Shuffle-gather gates within the wave (R8-verified): lane's unit ul
        // has gates i,f,c,o at quad lanes qb..qb+3; lane computes 4 rows.
        float h_[4];
        #pragma unroll
        for (int rr = 0; rr < 4; rr++) {
            float gi = __shfl(acc[rr], qb + 0, 64);
            float gf = __shfl(acc[rr], qb + 1, 64);
            float gg = __shfl(acc[rr], qb + 2, 64);
            float go = __shfl(acc[rr], qb + 3, 64);
            float ig = sigmoidf_(gi + bia);
            float fg = sigmoidf_(gf + bif);
            float gc = tanhf_(gg + big);
            float og = sigmoidf_(go + bio);
            creg[rr] = fg * creg[rr] + ig * gc;
            h_[rr] = og * tanhf_(creg[rr]);
        }

        // IMMEDIATE per-wave h store (tagged dwords; leaders l&7==0 store
        // unit pair (unit, unit+1) for 4 rows).  No block barrier on this path.
        float hp[4];
        #pragma unroll
        for (int rr = 0; rr < 4; rr++) hp[rr] = __shfl_xor(h_[rr], 4, 64);
        if ((l & 7) == 0) {
            #pragma unroll
            for (int rr = 0; rr < 4; rr++) {
                unsigned int pk = (unsigned int)(((unsigned)f2bf(h_[rr]) & 0xFFFEu) | wtag)
                                | ((unsigned int)(((unsigned)f2bf(hp[rr]) & 0xFFFEu) | wtag) << 16);
                void* sp = (void*)(hcur + (size_t)(rg * 16 + rb + rr) * U_ + unit);
                asm volatile("global_store_dword %0, %1, off sc0 sc1"
                             :: "v"(sp), "v"(pk) : "memory");
            }
        }

        // Dot partials: sum over this wave's 4 units per row (quad-leaders
        // contribute, then reduce across quads); wave-private dp, no barrier.
        #pragma unroll
        for (int rr = 0; rr < 4; rr++) {
            float s = ((l & 3) == 0) ? h_[rr] * wout : 0.f;
            s += __shfl_xor(s, 4, 64);
            s += __shfl_xor(s, 8, 64);
            if ((l & 15) == 0) dp[w][t & 31][rb + rr] = s;
        }

        // Per-wave flush every 32 steps (512 entries / 64 lanes = 8 each).
        if ((t & 31) == 31) {
            int t0 = t - 31;
            #pragma unroll
            for (int j = 0; j < 8; j++) {
                int idx = j * 64 + l;
                int tt = idx >> 4, row = idx & 15;
                atomicAdd(&dot[(size_t)(rg * 16 + row) * T_ + (t0 + tt)], dp[w][tt][row]);
            }
        }
    }
}

// ---------------------------------------------------------------------------
// Kernel 4: finale.  attention collapses to scalars:
//   coef_t = (t==0) ? 1 : sum_{j<t} att_W[t,j];  shift_t = (t==0) ? 0 : att_b[t]
//   out[b,t] = sigmoid(coef_t * dot[b,t] + shift_t * sum(out_W) + out_b)
// grid = 256 (one block per t).  Output dtype follows the input dtype flag.
// ---------------------------------------------------------------------------
__global__ __launch_bounds__(256) void finale(const float* __restrict__ attWf,
                                              const float* __restrict__ attbf,
                                              const float* __restrict__ outWf,
                                              const float* __restrict__ outbf,
                                              const float* __restrict__ dot,
                                              const int* __restrict__ flag,
                                              void* __restrict__ out) {
    __shared__ float red[256];
    int t = blockIdx.x, tid = threadIdx.x;
    int fg = *flag;

    float v = (tid < t) ? attWf[(size_t)t * T_ + tid] : 0.f;
    red[tid] = v; __syncthreads();
    for (int s = 128; s > 0; s >>= 1) { if (tid < s) red[tid] += red[tid + s]; __syncthreads(); }
    float coef = (t == 0) ? 1.f : red[0];
    __syncthreads();
    red[tid] = outWf[tid] + outWf[tid + 256]; __syncthreads();
    for (int s = 128; s > 0; s >>= 1) { if (tid < s) red[tid] += red[tid + s]; __syncthreads(); }
    float sumW = red[0];

    float base = ((t == 0) ? 0.f : attbf[t]) * sumW + outbf[0];

    if (tid < B_) {
        float s = sigmoidf_(coef * dot[(size_t)tid * T_ + t] + base);
        size_t idx = (size_t)tid * T_ + t;
        if (fg) ((float*)out)[idx] = s;
        else    ((u16*)out)[idx] = f2bf(s);
    }
}

// ---------------------------------------------------------------------------
extern "C" void kernel_launch(void* const* d_in, const int* in_sizes, int n_in,
                              void* d_out, int out_size, void* d_ws, size_t ws_size,
                              hipStream_t stream) {
    const void* x    = d_in[0];
    const void* kin  = d_in[1];
    const void* krec = d_in[2];
    const void* bias = d_in[3];
    const void* attW = d_in[4];
    const void* attb = d_in[5];
    const void* outW = d_in[6];
    const void* outb = d_in[7];

    if (ws_size < (size_t)WS_NEED) return;

    char* ws = (char*)d_ws;
    int*   flag  = (int*)(ws + WS_FLAG);
    u16*   xb    = (u16*)(ws + WS_XB);
    u16*   Wp    = (u16*)(ws + WS_WP);
    u16*   h2    = (u16*)(ws + WS_H2);
    float* dot   = (float*)(ws + WS_DOT);
    float* biasf = (float*)(ws + WS_BIASF);
    float* attWf = (float*)(ws + WS_ATTWF);
    float* attbf = (float*)(ws + WS_ATTBF);
    float* outWf = (float*)(ws + WS_OUTWF);
    float* outbf = (float*)(ws + WS_OUTBF);

    detect<<<1, 256, 0, stream>>>((const unsigned int*)kin, flag);
    convert<<<4556, 256, 0, stream>>>(x, bias, attW, attb, outW, outb, flag,
                                      xb, biasf, attWf, attbf, outWf, outbf, dot,
                                      (unsigned int*)h2);
    pack_w<<<576, 256, 0, stream>>>(kin, krec, flag, Wp);
    lstm_persist<<<64, 512, 0, stream>>>(xb, biasf, outWf, Wp, h2, dot);
    finale<<<256, 256, 0, stream>>>(attWf, attbf, outWf, outbf, dot, flag, d_out);
}

// Round 12
// 686.296 us; speedup vs baseline: 2.1749x; 2.1749x over previous
//
#include <hip/hip_runtime.h>
#include <hip/hip_bf16.h>
#include <string.h>

// Problem constants
#define B_ 64
#define T_ 256
#define F_ 64
#define U_ 512
#define G4_ 2048     // 4*U
#define KTOT 576     // F + U
#define KSTEPS 18    // KTOT/32

typedef __attribute__((ext_vector_type(8))) short short8;
typedef __attribute__((ext_vector_type(4))) float v4f;
typedef __attribute__((ext_vector_type(4))) int i4;
typedef unsigned short u16;

__device__ __forceinline__ float bf2f(u16 b) {
    unsigned int x = ((unsigned int)b) << 16;
    float f; memcpy(&f, &x, 4); return f;
}
__device__ __forceinline__ u16 f2bf(float f) {
    __hip_bfloat16 h = __float2bfloat16(f);
    u16 b; memcpy(&b, &h, 2); return b;
}
__device__ __forceinline__ float sigmoidf_(float x) { return 1.f / (1.f + __expf(-x)); }
__device__ __forceinline__ float tanhf_(float x) {   // clamped exp form (R8/R9-proven)
    float xc = fminf(15.f, fmaxf(-15.f, x));
    float e = __expf(2.f * xc);
    return (e - 1.f) / (e + 1.f);
}

// Dtype-flexible element load: fg=1 -> fp32, fg=0 -> bf16.
__device__ __forceinline__ float ldany(const void* p, size_t i, int fg) {
    return fg ? ((const float*)p)[i] : bf2f(((const u16*)p)[i]);
}

// Workspace layout (bytes; offsets 64-aligned) -- unchanged.
#define WS_FLAG   0             // int dtype-flag @0
#define WS_XB     64            // bf16 [T][B][F]          2,097,152
#define WS_WP     2097216       // bf16 packed weights     2,359,296
#define WS_H2     4456512       // bf16 [2][B][U]            131,072
#define WS_DOT    4718656       // fp32 [B][T]                65,536
#define WS_BIASF  4784192       // fp32 [4U]                   8,192
#define WS_ATTWF  4792384       // fp32 [T][T]               262,144
#define WS_ATTBF  5054528       // fp32 [T]                    1,024
#define WS_OUTWF  5055552       // fp32 [U]                    2,048
#define WS_OUTBF  5057600       // fp32 [1]                       64
#define WS_NEED   5057920

// ---------------------------------------------------------------------------
// Kernel 0: dtype detection (flag: 1 = fp32 inputs, 0 = bf16).
// ---------------------------------------------------------------------------
__global__ __launch_bounds__(256) void detect(const unsigned int* __restrict__ w,
                                              int* __restrict__ flag) {
    __shared__ int votes;
    if (threadIdx.x == 0) votes = 0;
    __syncthreads();
    unsigned int v = w[threadIdx.x];
    int e = (v >> 7) & 0xFF;
    if (e >= 100 && e <= 135) atomicAdd(&votes, 1);
    __syncthreads();
    if (threadIdx.x == 0) *flag = (votes < 200) ? 1 : 0;
}

// ---------------------------------------------------------------------------
// Kernel 1: canonicalize inputs.  x -> xb bf16 [T][B][F]; small arrays ->
// fp32; dot -> 0; h2 ping-pong -> 0 (tag 0 == stale for every expected tag;
// zeros are also the correct h_{-1} at t=0 where the check is skipped).
// ---------------------------------------------------------------------------
__global__ __launch_bounds__(256) void convert(const void* __restrict__ x,
                                               const void* __restrict__ bias,
                                               const void* __restrict__ attW,
                                               const void* __restrict__ attb,
                                               const void* __restrict__ outW,
                                               const void* __restrict__ outb,
                                               const int* __restrict__ flag,
                                               u16* __restrict__ xb,
                                               float* __restrict__ biasf,
                                               float* __restrict__ attWf,
                                               float* __restrict__ attbf,
                                               float* __restrict__ outWf,
                                               float* __restrict__ outbf,
                                               float* __restrict__ dot,
                                               unsigned int* __restrict__ h2z) {
    int fg = *flag;
    size_t i = (size_t)blockIdx.x * 256 + threadIdx.x;
    if (i < 1048576) {
        float v = ldany(x, i, fg);
        int b = (int)(i >> 14), t = (int)((i >> 6) & 255), f = (int)(i & 63);
        xb[((size_t)t * B_ + b) * F_ + f] = f2bf(v);
        return;
    }
    i -= 1048576;
    if (i < 2048)  { biasf[i] = ldany(bias, i, fg); return; }
    i -= 2048;
    if (i < 65536) { attWf[i] = ldany(attW, i, fg); return; }
    i -= 65536;
    if (i < 256)   { attbf[i] = ldany(attb, i, fg); return; }
    i -= 256;
    if (i < 512)   { outWf[i] = ldany(outW, i, fg); return; }
    i -= 512;
    if (i < 1)     { outbf[i] = ldany(outb, i, fg); return; }
    i -= 1;
    if (i < 16384) { dot[i] = 0.f; return; }
    i -= 16384;
    if (i < 32768) { h2z[i] = 0u; return; }   // both h ping-pong buffers
}

// ---------------------------------------------------------------------------
// Kernel 2: pack [kernel; rec_kernel] into MFMA-B fragments, cols c'=4u+gate.
// Lane l of fragment (nt, ks) supplies B[k=ks*32+(l>>4)*8+j][col=nt*16+(l&15)].
// ---------------------------------------------------------------------------
__global__ __launch_bounds__(256) void pack_w(const void* __restrict__ kin,
                                              const void* __restrict__ krec,
                                              const int* __restrict__ flag,
                                              u16* __restrict__ Wp) {
    int fg = *flag;
    int gid = blockIdx.x * 256 + threadIdx.x;   // grid = 576*256 == 128*18*64
    int lane = gid & 63;
    int frag = gid >> 6;
    int nt = frag / KSTEPS;
    int ks = frag - nt * KSTEPS;
    int kbase = ks * 32 + (lane >> 4) * 8;
    int cp = nt * 16 + (lane & 15);
    int u = cp >> 2, gate = cp & 3;
    int C = gate * U_ + u;
    short8 v;
    for (int j = 0; j < 8; j++) {
        int k = kbase + j;
        float w = (k < F_) ? ldany(kin, (size_t)k * G4_ + C, fg)
                           : ldany(krec, (size_t)(k - F_) * G4_ + C, fg);
        v[j] = (short)f2bf(w);
    }
    *reinterpret_cast<short8*>(Wp + (size_t)gid * 8) = v;
}

// ---------------------------------------------------------------------------
// Kernel 3: PERSISTENT LSTM -- exact R10 structure (686 us best-known) with
// ONE change: gbuf gate columns remapped from stride-4 to stride-5
// (col = 5*u_local + gate, 5 coprime with 32 banks).  R10's epilogue read
// &gbuf[er][4*ui] had bank = (4*er+4*ui+g)%32 -> 4 lanes/bank on each of 4
// scalar reads (the bulk of R10's 10.5M SQ_LDS_BANK_CONFLICT).  Stride-5
// makes reads conflict-free; writer scatter stays <=2-way (free, m136).
// Everything else -- partition (rg=bid&3 x gu=bid>>2), per-wave VGPR
// weights, 2-row polls (sc1 + in-band LSB tags), two barriers/step,
// block-shared dp flush -- is byte-for-byte R10 (R11's deviations each
// regressed: spread polls 2x FETCH, per-wave flush 8x atomics, redundant
// epilogue VALU).
// ---------------------------------------------------------------------------
__global__ __launch_bounds__(512, 2) void lstm_persist(const u16* __restrict__ xb,
                                                       const float* __restrict__ biasf,
                                                       const float* __restrict__ outWf,
                                                       const u16* __restrict__ Wp,
                                                       u16* __restrict__ h2,
                                                       float* __restrict__ dot) {
    __shared__ __align__(16) u16 stage[16 * 520];   // 16 rows x 512 h (+8 pad)
    __shared__ __align__(16) float gbuf[16][164];   // 16 rows x (5*32+4) gate cols
    __shared__ float dp[32][16];                    // dot partials: 32 steps x 16 rows

    int tid = threadIdx.x;
    int bid = blockIdx.x;
    int rg = bid & 3;                     // row-group: rows [16rg, 16rg+16)
    int gu = bid >> 2;                    // unit-group: units [32gu, 32gu+32)
    int w = tid >> 6, l = tid & 63;
    int nt = gu * 8 + w;                  // this wave's global n-tile

    // Weights into VGPRs: 18 fragments, loaded once.
    short8 W[KSTEPS];
    #pragma unroll
    for (int ks = 0; ks < KSTEPS; ks++)
        W[ks] = *reinterpret_cast<const short8*>(Wp + ((size_t)(nt * KSTEPS + ks) * 64 + l) * 8);

    // MFMA roles.
    int arow = rg * 16 + (l & 15);        // A row (global batch index)
    int koff = (l >> 4) * 8;              // k-chunk within a 32-wide ks
    // Poll/stage roles: wave w handles local rows 2w, 2w+1.
    int plr = 2 * w + (l >> 5);           // local row polled by this lane
    int pcol = (l & 31) * 16;             // u16 column of this lane's 32B chunk
    // Elementwise roles: thread = (row = tid>>5, ui = tid&31).
    int er = tid >> 5;
    int ui = tid & 31;
    int unit = gu * 32 + ui;
    float bia = biasf[0 * U_ + unit], bif = biasf[1 * U_ + unit];
    float big = biasf[2 * U_ + unit], bio = biasf[3 * U_ + unit];
    float wout = outWf[unit];
    float c = 0.f;

    for (int t = 0; t < T_; t++) {
        u16* hcur = h2 + (size_t)(t & 1) * (B_ * U_);
        const u16* hprev = h2 + (size_t)((t + 1) & 1) * (B_ * U_);
        unsigned int wtag = ((unsigned)(t >> 1) & 1u) ^ 1u;
        unsigned int rpat = ((((unsigned)(t - 1) >> 1) & 1u) ^ 1u) * 0x00010001u;

        // Poll this wave's 2 rows of h_{t-1}: 2 coherent 16B loads per lane,
        // accept when all 8 dwords are fresh wave-unanimously.
        i4 q0, q1;
        {
            const void* bp = (const void*)(hprev + (size_t)(rg * 16 + plr) * U_ + pcol);
            int spins = 0;
            for (;;) {
                asm volatile(
                    "global_load_dwordx4 %0, %2, off sc0 sc1\n\t"
                    "global_load_dwordx4 %1, %2, off offset:16 sc0 sc1\n\t"
                    "s_waitcnt vmcnt(0)"
                    : "=v"(q0), "=v"(q1) : "v"(bp) : "memory");
                if (t == 0) break;        // zeros are the correct h_{-1}
                unsigned bad = 0;
                bad |= (((unsigned)q0[0]) ^ rpat) & 0x00010001u;
                bad |= (((unsigned)q0[1]) ^ rpat) & 0x00010001u;
                bad |= (((unsigned)q0[2]) ^ rpat) & 0x00010001u;
                bad |= (((unsigned)q0[3]) ^ rpat) & 0x00010001u;
                bad |= (((unsigned)q1[0]) ^ rpat) & 0x00010001u;
                bad |= (((unsigned)q1[1]) ^ rpat) & 0x00010001u;
                bad |= (((unsigned)q1[2]) ^ rpat) & 0x00010001u;
                bad |= (((unsigned)q1[3]) ^ rpat) & 0x00010001u;
                if (__ballot(bad == 0) == ~0ull) break;
                if (++spins > (1 << 14)) break;   // bailout: never hang
                __builtin_amdgcn_s_sleep(2);      // short backoff
            }
        }
        // Stage into LDS (row-major, 520-u16 stride).
        *reinterpret_cast<i4*>(&stage[plr * 520 + pcol])     = q0;
        *reinterpret_cast<i4*>(&stage[plr * 520 + pcol + 8]) = q1;
        __syncthreads();   // barrier 1: stage ready

        // MFMA: x-part from global (L2-hot), h-part from staged LDS.
        const u16* xrow = xb + ((size_t)t * B_ + arow) * F_;
        short8 a0 = *reinterpret_cast<const short8*>(xrow + koff);
        short8 a1 = *reinterpret_cast<const short8*>(xrow + 32 + koff);
        v4f acc0 = {0.f, 0.f, 0.f, 0.f}, acc1 = {0.f, 0.f, 0.f, 0.f};
        acc0 = __builtin_amdgcn_mfma_f32_16x16x32_bf16(a0, W[0], acc0, 0, 0, 0);
        acc1 = __builtin_amdgcn_mfma_f32_16x16x32_bf16(a1, W[1], acc1, 0, 0, 0);
        #pragma unroll
        for (int ks = 2; ks < KSTEPS; ks += 2) {
            short8 ah0 = *reinterpret_cast<const short8*>(
                &stage[(l & 15) * 520 + (ks - 2) * 32 + koff]);
            short8 ah1 = *reinterpret_cast<const short8*>(
                &stage[(l & 15) * 520 + (ks - 1) * 32 + koff]);
            acc0 = __builtin_amdgcn_mfma_f32_16x16x32_bf16(ah0, W[ks],     acc0, 0, 0, 0);
            acc1 = __builtin_amdgcn_mfma_f32_16x16x32_bf16(ah1, W[ks + 1], acc1, 0, 0, 0);
        }
        v4f acc = acc0 + acc1;

        // D layout: lane holds D[row=(l>>4)*4+rr][col=l&15].  Col c=16w+(l&15)
        // is unit u=c>>2, gate g=c&3 -> gbuf offset 5u+g (stride-5, bank-clean).
        {
            int c0 = 16 * w + (l & 15);
            int coff = 5 * (c0 >> 2) + (c0 & 3);
            int rb = (l >> 4) * 4;
            #pragma unroll
            for (int rr = 0; rr < 4; rr++)
                gbuf[rb + rr][coff] = acc[rr];
        }
        __syncthreads();   // barrier 2: gbuf ready

        // Elementwise: 1 unit per thread.  Gates at gbuf[er][5*ui + g].
        {
            const float* gr = &gbuf[er][5 * ui];
            float ig = sigmoidf_(gr[0] + bia);
            float fg = sigmoidf_(gr[1] + bif);
            float gc = tanhf_(gr[2] + big);
            float og = sigmoidf_(gr[3] + bio);
            c = fg * c + ig * gc;
            float h = og * tanhf_(c);

            // Pack unit pair into a dword with LSB tags; even-ui lane stores.
            float hp = __shfl_xor(h, 1, 64);
            if ((ui & 1) == 0) {
                unsigned int pk = (unsigned int)(((unsigned)f2bf(h)  & 0xFFFEu) | wtag)
                                | ((unsigned int)(((unsigned)f2bf(hp) & 0xFFFEu) | wtag) << 16);
                void* sp = (void*)(hcur + (size_t)(rg * 16 + er) * U_ + unit);
                asm volatile("global_store_dword %0, %1, off sc0 sc1"
                             :: "v"(sp), "v"(pk) : "memory");
            }

            // dot partial over this block's 32 units of row er.
            float s = h * wout;
            s += __shfl_xor(s, 1, 64);
            s += __shfl_xor(s, 2, 64);
            s += __shfl_xor(s, 4, 64);
            s += __shfl_xor(s, 8, 64);
            s += __shfl_xor(s, 16, 64);
            if (ui == 0) dp[t & 31][er] = s;
        }

        // Flush dot partials every 32 steps (512 entries, 1 per thread).
        if ((t & 31) == 31) {
            __syncthreads();
            int t0 = t - 31;
            int tt = tid >> 4, row = tid & 15;
            atomicAdd(&dot[(size_t)(rg * 16 + row) * T_ + (t0 + tt)], dp[tt][row]);
        }
    }
}

// ---------------------------------------------------------------------------
// Kernel 4: finale.  attention collapses to scalars:
//   coef_t = (t==0) ? 1 : sum_{j<t} att_W[t,j];  shift_t = (t==0) ? 0 : att_b[t]
//   out[b,t] = sigmoid(coef_t * dot[b,t] + shift_t * sum(out_W) + out_b)
// grid = 256 (one block per t).  Output dtype follows the input dtype flag.
// ---------------------------------------------------------------------------
__global__ __launch_bounds__(256) void finale(const float* __restrict__ attWf,
                                              const float* __restrict__ attbf,
                                              const float* __restrict__ outWf,
                                              const float* __restrict__ outbf,
                                              const float* __restrict__ dot,
                                              const int* __restrict__ flag,
                                              void* __restrict__ out) {
    __shared__ float red[256];
    int t = blockIdx.x, tid = threadIdx.x;
    int fg = *flag;

    float v = (tid < t) ? attWf[(size_t)t * T_ + tid] : 0.f;
    red[tid] = v; __syncthreads();
    for (int s = 128; s > 0; s >>= 1) { if (tid < s) red[tid] += red[tid + s]; __syncthreads(); }
    float coef = (t == 0) ? 1.f : red[0];
    __syncthreads();
    red[tid] = outWf[tid] + outWf[tid + 256]; __syncthreads();
    for (int s = 128; s > 0; s >>= 1) { if (tid < s) red[tid] += red[tid + s]; __syncthreads(); }
    float sumW = red[0];

    float base = ((t == 0) ? 0.f : attbf[t]) * sumW + outbf[0];

    if (tid < B_) {
        float s = sigmoidf_(coef * dot[(size_t)tid * T_ + t] + base);
        size_t idx = (size_t)tid * T_ + t;
        if (fg) ((float*)out)[idx] = s;
        else    ((u16*)out)[idx] = f2bf(s);
    }
}

// ---------------------------------------------------------------------------
extern "C" void kernel_launch(void* const* d_in, const int* in_sizes, int n_in,
                              void* d_out, int out_size, void* d_ws, size_t ws_size,
                              hipStream_t stream) {
    const void* x    = d_in[0];
    const void* kin  = d_in[1];
    const void* krec = d_in[2];
    const void* bias = d_in[3];
    const void* attW = d_in[4];
    const void* attb = d_in[5];
    const void* outW = d_in[6];
    const void* outb = d_in[7];

    if (ws_size < (size_t)WS_NEED) return;

    char* ws = (char*)d_ws;
    int*   flag  = (int*)(ws + WS_FLAG);
    u16*   xb    = (u16*)(ws + WS_XB);
    u16*   Wp    = (u16*)(ws + WS_WP);
    u16*   h2    = (u16*)(ws + WS_H2);
    float* dot   = (float*)(ws + WS_DOT);
    float* biasf = (float*)(ws + WS_BIASF);
    float* attWf = (float*)(ws + WS_ATTWF);
    float* attbf = (float*)(ws + WS_ATTBF);
    float* outWf = (float*)(ws + WS_OUTWF);
    float* outbf = (float*)(ws + WS_OUTBF);

    detect<<<1, 256, 0, stream>>>((const unsigned int*)kin, flag);
    convert<<<4556, 256, 0, stream>>>(x, bias, attW, attb, outW, outb, flag,
                                      xb, biasf, attWf, attbf, outWf, outbf, dot,
                                      (unsigned int*)h2);
    pack_w<<<576, 256, 0, stream>>>(kin, krec, flag, Wp);
    lstm_persist<<<64, 512, 0, stream>>>(xb, biasf, outWf, Wp, h2, dot);
    finale<<<256, 256, 0, stream>>>(attWf, attbf, outWf, outbf, dot, flag, d_out);
}